// Round 10
// baseline (214.115 us; speedup 1.0000x reference)
//
#include <hip/hip_runtime.h>
#include <math.h>

#define EPS32 1.1920928955078125e-07f
#define NSP 32768          // 2*128*128 spatial positions
#define HB 128             // heatmap blocks

// Clang native vector types — required for __builtin_nontemporal_* (HIP_vector_type structs are rejected)
typedef float v4f __attribute__((ext_vector_type(4)));
typedef float v2f __attribute__((ext_vector_type(2)));

// ---------------- ws layout (float units) ----------------
// 0     : partial[128]
// 1024  : hmv[32768]

__device__ __forceinline__ float gauss_radius(float h, float w) {
#pragma clang fp contract(off)
    const float mo = 0.1f;
    float b1 = h + w;
    float c1 = w * h * (1.0f - mo) / (1.0f + mo);
    float r1 = (b1 + sqrtf(fmaxf(b1 * b1 - 4.0f * c1, 0.0f))) / 2.0f;
    float b2 = 2.0f * (h + w);
    float c2 = (1.0f - mo) * w * h;
    float r2 = (b2 + sqrtf(fmaxf(b2 * b2 - 16.0f * c2, 0.0f))) / 2.0f;
    float b3 = -2.0f * mo * (h + w);
    float c3 = (mo - 1.0f) * w * h;
    float r3 = (b3 + sqrtf(fmaxf(b3 * b3 - 16.0f * mo * c3, 0.0f))) / 2.0f;
    return fminf(fminf(r1, r2), r3);
}

// Heatmap: 128 blocks, per-block in-LDS box params + per-block partial sum.
__global__ void k_heat(const float* __restrict__ boxes, int N,
                       float* __restrict__ hmv, float* __restrict__ partial) {
    int bx = blockIdx.x;
    int tid = threadIdx.x;
    __shared__ int   s_cxi[128], s_cyi[128], s_czi[128], s_rx[128], s_rz[128];
    __shared__ float s_ix[128], s_iz[128];
    if (tid < N) {
#pragma clang fp contract(off)
        int b = tid;
        float x = boxes[b * 9 + 0];
        float y = boxes[b * 9 + 1];
        float z = boxes[b * 9 + 2];
        float wf = boxes[b * 9 + 3] / 0.1f / 8.0f;
        float lf = boxes[b * 9 + 4] / 0.1f / 8.0f;
        float hf = boxes[b * 9 + 5] / 0.2f / 8.0f;
        float r_xy = gauss_radius(lf, wf);
        float r_z  = fmaxf(gauss_radius(lf, hf), gauss_radius(wf, hf));
        int rx = max(2, (int)truncf(r_xy / 0.4f));
        int rz = max(2, (int)truncf(r_z / 1.0f));
        float cx = (x + 51.2f) / 0.4f;
        float cy = (y + 51.2f) / 0.4f;
        float cz = (z + 5.0f) / 1.0f;
        int cxi = (int)cx, cyi = (int)cy, czi = (int)cz;
        int valid = (wf > 0.0f) && (lf > 0.0f) &&
                    cxi >= 0 && cxi < 128 && cyi >= 0 && cyi < 128 &&
                    czi >= 0 && czi <= 1;
        float sx = (2.0f * (float)rx + 1.0f) / 6.0f;
        float sz = (2.0f * (float)rz + 1.0f) / 6.0f;
        s_cxi[b] = cxi;
        s_cyi[b] = cyi;
        s_czi[b] = czi;
        s_rx[b]  = valid ? rx : -1;   // rx=-1 makes window test always fail
        s_rz[b]  = rz;
        s_ix[b]  = 1.0f / (2.0f * sx * sx);
        s_iz[b]  = 1.0f / (2.0f * sz * sz);
    }
    __syncthreads();

    int i = bx * 256 + tid;
    int y = i & 127, x = (i >> 7) & 127, zc = i >> 14;
    float m = 0.0f;
    for (int b = 0; b < N; ++b) {
        int rx = s_rx[b];
        int dx = x - s_cxi[b];
        if (dx > rx || dx < -rx) continue;
        int dy = y - s_cyi[b];
        if (dy > rx || dy < -rx) continue;
        int rz = s_rz[b];
        int dz = zc - s_czi[b];
        if (dz > rz || dz < -rz) continue;
        float e = (float)(dx * dx + dy * dy) * s_ix[b]
                + (float)(dz * dz) * s_iz[b];
        float g = expf(-e);
        if (g >= EPS32) m = fmaxf(m, g);
    }
    hmv[i] = m;
    __shared__ float sm[256];
    sm[tid] = m;
    __syncthreads();
    for (int s = 128; s > 0; s >>= 1) {
        if (tid < s) sm[tid] += sm[tid + s];
        __syncthreads();
    }
    if (tid == 0) partial[bx] = sm[0];
}

// ONE-PASS pool + GEMM + epilogue. Block = 64-sp tile x all 128 o.
// R3..R9 lesson: k_final was pinned at ~40us regardless of inner-loop form;
// the invariant was the memory STRUCTURE (pooled ws round-trip + x16 pooled
// re-read as 8B strided loads). This kernel reads everything exactly once:
// student 67MB (nt), W 32KB/block (L2), teacher 16.8MB (nt), out 16.8MB (nt).
// LDS: P-tile [c][sp] 16KB + W [c][o] 32KB = 49KB -> 2-3 blocks/CU.
// GEMM inner: 3x ds_read_b128 (conflict-free / 2-way=free) + 32 FMA per c.
__global__ __launch_bounds__(256, 2)
void k_gemm(const float* __restrict__ S, const float* __restrict__ T,
            const float* __restrict__ W, const float* __restrict__ Bb,
            const float* __restrict__ hmv, const float* __restrict__ partial,
            float* __restrict__ out) {
    __shared__ float sP[64 * 64];    // [c][sp]
    __shared__ float sW[64 * 128];   // [c][o]  (transposed W)
    __shared__ float s_scale;

    int tid = threadIdx.x;
    int b   = blockIdx.x;            // 512 sp-tiles of 64
    int d   = b >> 8;                // s = b*64 -> d = s>>14
    int h   = (b >> 1) & 127;        //              h = (s>>7)&127
    int w0  = (b & 1) * 64;          //              w0 = s&127
    int zl  = d ? 5 : 1;

    if (tid < 64) {
        float v = partial[tid] + partial[tid + 64];
        for (int off = 32; off > 0; off >>= 1) v += __shfl_down(v, off, 64);
        if (tid == 0) s_scale = 10.0f / (v + 1e-4f);
    }

    // ---- stage W transposed: thread loads W[o][c0..c0+32), scatters to sW[c][o]
    {
        int o  = tid >> 1;
        int c0 = (tid & 1) * 32;
        const v4f* Wg = (const v4f*)(W + o * 64 + c0);
#pragma unroll
        for (int k = 0; k < 8; ++k) {
            v4f wv = Wg[k];
            int c = c0 + 4 * k;
            sW[(c    ) * 128 + o] = wv.x;   // bank = o%32; 2 lanes/o -> 2-way = free
            sW[(c + 1) * 128 + o] = wv.y;
            sW[(c + 2) * 128 + o] = wv.z;
            sW[(c + 3) * 128 + o] = wv.w;
        }
    }

    // ---- pool stage: 1024 tasks (c, q): c=T>>4, q=T&15 (q = 4-sp quad)
    {
#pragma unroll
        for (int i = 0; i < 4; ++i) {
            int Ti = tid + 256 * i;
            int c = Ti >> 4, q = Ti & 15;
            long base = (long)(c * 8 + zl) * 65536 + (2 * h) * 256 + 2 * (w0 + 4 * q);
            const v4f* r0 = (const v4f*)(S + base);            // z0, row 2h
            const v4f* r1 = (const v4f*)(S + base + 256);      // z0, row 2h+1
            const v4f* r2 = (const v4f*)(S + base + 65536);    // z1, row 2h
            const v4f* r3 = (const v4f*)(S + base + 65536 + 256);
            v4f a0 = __builtin_nontemporal_load(&r0[0]);
            v4f a1 = __builtin_nontemporal_load(&r0[1]);
            v4f b0 = __builtin_nontemporal_load(&r1[0]);
            v4f b1 = __builtin_nontemporal_load(&r1[1]);
            v4f e0 = __builtin_nontemporal_load(&r2[0]);
            v4f e1 = __builtin_nontemporal_load(&r2[1]);
            v4f f0 = __builtin_nontemporal_load(&r3[0]);
            v4f f1 = __builtin_nontemporal_load(&r3[1]);
            v4f pv;
            pv.x = (((a0.x + a0.y) + (b0.x + b0.y)) + ((e0.x + e0.y) + (f0.x + f0.y))) * 0.125f;
            pv.y = (((a0.z + a0.w) + (b0.z + b0.w)) + ((e0.z + e0.w) + (f0.z + f0.w))) * 0.125f;
            pv.z = (((a1.x + a1.y) + (b1.x + b1.y)) + ((e1.x + e1.y) + (f1.x + f1.y))) * 0.125f;
            pv.w = (((a1.z + a1.w) + (b1.z + b1.w)) + ((e1.z + e1.w) + (f1.z + f1.w))) * 0.125f;
            *(v4f*)&sP[c * 64 + 4 * q] = pv;   // bank 4q%32: 2-way = free
        }
    }

    __syncthreads();

    // ---- GEMM: og = tid>>4 (8 o each), sq = tid&15 (4 sp each)
    int og = tid >> 4, sq = tid & 15;
    int o0 = og * 8;

    v4f acc[8];
#pragma unroll
    for (int oo = 0; oo < 8; ++oo) {
        float bv = Bb[o0 + oo];
        acc[oo] = (v4f){bv, bv, bv, bv};
    }

    const v4f* Pc = (const v4f*)sP;   // [c][16 sp-quads]
    const v4f* Wc = (const v4f*)sW;   // [c][32 o-quads]
#pragma unroll 8
    for (int c = 0; c < 64; ++c) {
        v4f p  = Pc[c * 16 + sq];          // 16 addrs, banks sq*4: 2-way = free
        v4f wa = Wc[c * 32 + og * 2];      // 4 addrs, banks og*8: broadcast, conflict-free
        v4f wb = Wc[c * 32 + og * 2 + 1];
        acc[0] += wa.x * p;
        acc[1] += wa.y * p;
        acc[2] += wa.z * p;
        acc[3] += wa.w * p;
        acc[4] += wb.x * p;
        acc[5] += wb.y * p;
        acc[6] += wb.z * p;
        acc[7] += wb.w * p;
    }

    // ---- epilogue: |acc - T| * hmv * scale, all float4, read/write-once -> nt
    float sc = s_scale;
    v4f hm = *(const v4f*)&hmv[b * 64 + sq * 4];
    v4f hw = hm * sc;
    const v4f* T4 = (const v4f*)T;
    v4f* O4 = (v4f*)out;
    long base_o = (long)o0 * (NSP / 4) + b * 16 + sq;
#pragma unroll
    for (int oo = 0; oo < 8; ++oo) {
        v4f tv = __builtin_nontemporal_load(&T4[base_o + (long)oo * (NSP / 4)]);
        v4f df = acc[oo] - tv;
        v4f r;
        r.x = fabsf(df.x) * hw.x;
        r.y = fabsf(df.y) * hw.y;
        r.z = fabsf(df.z) * hw.z;
        r.w = fabsf(df.w) * hw.w;
        __builtin_nontemporal_store(r, &O4[base_o + (long)oo * (NSP / 4)]);
    }
}

extern "C" void kernel_launch(void* const* d_in, const int* in_sizes, int n_in,
                              void* d_out, int out_size, void* d_ws, size_t ws_size,
                              hipStream_t stream) {
    const float* boxes   = (const float*)d_in[0];
    // d_in[1] = gt_labels_3d (unused by the reference output)
    const float* teacher = (const float*)d_in[2];
    const float* student = (const float*)d_in[3];
    const float* conv_w  = (const float*)d_in[4];
    const float* conv_b  = (const float*)d_in[5];
    float* out = (float*)d_out;

    int N = in_sizes[0] / 9;
    if (N > 128) N = 128;

    float* wsF     = (float*)d_ws;
    float* partial = wsF;
    float* hmv     = wsF + 1024;
    // ws need: (1024 + 32768) * 4 B = 135 KB  (harness provides ~536 MB)

    k_heat<<<HB, 256, 0, stream>>>(boxes, N, hmv, partial);
    k_gemm<<<NSP / 64, 256, 0, stream>>>(student, teacher, conv_w, conv_b,
                                         hmv, partial, out);
}